// Round 5
// baseline (287.706 us; speedup 1.0000x reference)
//
#include <hip/hip_runtime.h>
#include <hip/hip_bf16.h>
#include <float.h>

// Problem constants
constexpr int B  = 64;
constexpr int C  = 256;
constexpr int HW = 1024;   // 32*32
constexpr int K  = 1024;
constexpr float BETA = 0.25f;
constexpr float NTOT_INV = 1.0f / 16777216.0f;  // 1 / (64*256*32*32)

typedef __attribute__((ext_vector_type(8))) short bf16x8;
typedef __attribute__((ext_vector_type(4))) float floatx4;

union U16 { uint4 u; bf16x8 b; };

__device__ inline unsigned short f2bf(float x) {
    unsigned u = __float_as_uint(x);
    return (unsigned short)((u + 0x7FFFu + ((u >> 16) & 1u)) >> 16);  // RNE
}

// --- kernel 1: emb fp32 -> bf16 TILED [ks=ch/32][code][ch%32] + esq1 ---
// grid 256 x 256 threads. Also zeroes loss accumulators.
__global__ __launch_bounds__(256) void prep_kernel(const float* __restrict__ emb,
                                                   short* __restrict__ ebf2,
                                                   float* __restrict__ esq1,
                                                   float* __restrict__ acc_loss) {
    if (blockIdx.x == 0 && threadIdx.x < 2) acc_loss[threadIdx.x] = 0.0f;
    const int wid  = threadIdx.x >> 6;
    const int lane = threadIdx.x & 63;
    const int k    = blockIdx.x * 4 + wid;
    const float4 v = *(const float4*)(emb + (size_t)k * C + lane * 4);
    ushort4 pk = { f2bf(v.x), f2bf(v.y), f2bf(v.z), f2bf(v.w) };
    // c = lane*4 ; ks = lane>>3 ; c&31 = (lane&7)*4
    *(ushort4*)&ebf2[((size_t)(lane >> 3) * K + k) * 32 + (lane & 7) * 4] = pk;
    float s = v.x * v.x + v.y * v.y + v.z * v.z + v.w * v.w;
#pragma unroll
    for (int off = 32; off > 0; off >>= 1) s += __shfl_down(s, off, 64);
    if (lane == 0) esq1[k] = 1.0f + s;
}

// --- kernel 2: fused transpose + distances + argmin.
// 4 waves/block, 64 tokens/block, wave w handles codes [w*256, w*256+256).
// zfrag re-read from LDS inside the ks loop (no 128-VGPR zfrag array) so the
// body fits the 128-reg cap of launch_bounds(256,4) -> 4 waves/SIMD, no spill.
// grid 1024 x 256.
__global__ __launch_bounds__(256, 4) void vq_dist(const float* __restrict__ z,
                                                  const short* __restrict__ ebf2,
                                                  const float* __restrict__ esq1,
                                                  unsigned short* __restrict__ inds) {
    // transpose buffer: [32 ch-blocks][64 tok][8 ch] bf16 = 32 KB
    __shared__ short Zs[32 * 512];
    __shared__ unsigned int warr[4 * 64];

    const int tid = threadIdx.x;
    const int wid = tid >> 6;      // wave 0..3
    const int L   = tid & 63;      // lane
    const int q   = L >> 4;        // quad
    const int l15 = L & 15;

    const int bidx = blockIdx.x;
    const int b    = bidx >> 4;           // batch
    const int hw0  = (bidx & 15) * 64;    // position tile base
    const float* zb = z + (size_t)b * C * HW + hw0;

    // ---- phase 1: cooperative transpose, wave w does channels [w*64, w*64+64) ----
#pragma unroll 4
    for (int i = 0; i < 16; ++i) {
        const int c = wid * 64 + i * 4;
        float v0 = zb[(size_t)(c + 0) * HW + L];
        float v1 = zb[(size_t)(c + 1) * HW + L];
        float v2 = zb[(size_t)(c + 2) * HW + L];
        float v3 = zb[(size_t)(c + 3) * HW + L];
        ushort4 pk = { f2bf(v0), f2bf(v1), f2bf(v2), f2bf(v3) };
        *(ushort4*)&Zs[(c >> 3) * 512 + L * 8 + (c & 7)] = pk;
    }
    __syncthreads();

    // ---- phase 2: K loop; A-frags from tiled ebf2 (coalesced 1KB), z-frags
    // from LDS per ks step ----
    unsigned int best[4] = {0xFFFFFFFFu, 0xFFFFFFFFu, 0xFFFFFFFFu, 0xFFFFFFFFu};

    for (int kk = 0; kk < 4; ++kk) {
        const int k0 = wid * 256 + kk * 64;
        floatx4 acc[4][4];   // [m code tile][t token tile]
#pragma unroll
        for (int m = 0; m < 4; ++m)
#pragma unroll
            for (int t = 0; t < 4; ++t) acc[m][t] = (floatx4){0.f, 0.f, 0.f, 0.f};

#pragma unroll
        for (int ks = 0; ks < 8; ++ks) {
            U16 a[4];
#pragma unroll
            for (int m = 0; m < 4; ++m)
                a[m].u = *(const uint4*)(ebf2 + ((size_t)ks * K + (k0 + m * 16 + l15)) * 32 + q * 8);
            bf16x8 zf[4];
#pragma unroll
            for (int t = 0; t < 4; ++t)
                zf[t] = *(const bf16x8*)&Zs[(ks * 4 + q) * 512 + (t * 16 + l15) * 8];
#pragma unroll
            for (int m = 0; m < 4; ++m)
#pragma unroll
                for (int t = 0; t < 4; ++t)
                    acc[m][t] = __builtin_amdgcn_mfma_f32_16x16x32_bf16(a[m].b, zf[t], acc[m][t], 0, 0, 0);
        }

        // distances + packed argmin (d positive: bits monotone; low 10 bits = code)
#pragma unroll
        for (int m = 0; m < 4; ++m) {
            const float4 eq = *(const float4*)&esq1[k0 + m * 16 + q * 4];
            const float eqa[4] = {eq.x, eq.y, eq.z, eq.w};
#pragma unroll
            for (int r = 0; r < 4; ++r) {
                const unsigned int code = (unsigned int)(k0 + m * 16 + q * 4 + r);
#pragma unroll
                for (int t = 0; t < 4; ++t) {
                    float d = fmaf(-2.0f, acc[m][t][r], eqa[r]);
                    unsigned int u = (__float_as_uint(d) & 0xFFFFFC00u) | code;
                    best[t] = best[t] < u ? best[t] : u;
                }
            }
        }
    }

    // ---- phase 3: butterfly argmin across quads, then across waves via LDS ----
#pragma unroll
    for (int t = 0; t < 4; ++t) {
        unsigned int o = (unsigned int)__shfl_xor((int)best[t], 16, 64);
        best[t] = best[t] < o ? best[t] : o;
        o = (unsigned int)__shfl_xor((int)best[t], 32, 64);
        best[t] = best[t] < o ? best[t] : o;
    }
    warr[wid * 64 + L] = (q == 0) ? best[0] : (q == 1) ? best[1] : (q == 2) ? best[2] : best[3];
    __syncthreads();

    if (tid < 64) {
        unsigned int u0 = warr[tid];
        unsigned int u1 = warr[64 + tid];
        unsigned int u2 = warr[128 + tid];
        unsigned int u3 = warr[192 + tid];
        u0 = u0 < u1 ? u0 : u1;
        u2 = u2 < u3 ? u2 : u3;
        u0 = u0 < u2 ? u0 : u2;
        inds[bidx * 64 + tid] = (unsigned short)(u0 & 1023u);
    }
}

// --- kernel 3: streaming output + loss, hw-major, NO global gathers.
// Each block stages its 8 emb columns into LDS (Et[8][1024] fp32 = 32KB),
// then the per-token codebook lookup is a cheap LDS read (random-bank ~2-way).
// grid 2048 (b x ch-octet) x 256 threads.
__global__ __launch_bounds__(256) void vq_out(const float* __restrict__ z,
                                              const float* __restrict__ emb,
                                              const unsigned short* __restrict__ inds,
                                              float* __restrict__ out,
                                              float* __restrict__ acc_loss) {
    __shared__ float Et[8][1024];   // 32 KB: emb[:, c0..c0+7] transposed
    __shared__ float lsum[2];
    const int tid = threadIdx.x;
    const int wv  = tid >> 6;
    const int L   = tid & 63;
    const int b   = blockIdx.x >> 5;
    const int c0  = (blockIdx.x & 31) * 8;

    if (tid == 0) { lsum[0] = 0.0f; lsum[1] = 0.0f; }

    // ---- stage Et: rows r = tid, tid+256, tid+512, tid+768 (32B/row, 1 line) ----
#pragma unroll
    for (int i = 0; i < 4; ++i) {
        const int r = i * 256 + tid;
        float4 e0 = *(const float4*)(emb + (size_t)r * C + c0);
        float4 e1 = *(const float4*)(emb + (size_t)r * C + c0 + 4);
        Et[0][r] = e0.x; Et[1][r] = e0.y; Et[2][r] = e0.z; Et[3][r] = e0.w;
        Et[4][r] = e1.x; Et[5][r] = e1.y; Et[6][r] = e1.z; Et[7][r] = e1.w;
    }
    __syncthreads();

    const int ca = c0 + wv * 2;                               // even channel
    const float* za  = z   + ((size_t)b * C + ca) * HW;
    const float* zb2 = za + HW;
    float* oa = out + ((size_t)b * C + ca) * HW;
    float* ob = oa + HW;
    const unsigned short* ib = inds + b * HW;
    const int r0 = wv * 2;                                    // Et row pair

    float s_sq = 0.0f, s_d = 0.0f;
#pragma unroll
    for (int hc = 0; hc < 4; ++hc) {
        const int hw = hc * 256 + L * 4;
        ushort4 kmv = *(const ushort4*)(ib + hw);
        float4 z0 = *(const float4*)(za + hw);
        float4 z1 = *(const float4*)(zb2 + hw);
        const unsigned short kma[4] = {kmv.x, kmv.y, kmv.z, kmv.w};
        float e0[4], e1[4];
#pragma unroll
        for (int j = 0; j < 4; ++j) {
            e0[j] = Et[r0][kma[j]];
            e1[j] = Et[r0 + 1][kma[j]];
        }
        const float z0a[4] = {z0.x, z0.y, z0.z, z0.w};
        const float z1a[4] = {z1.x, z1.y, z1.z, z1.w};
        float o0a[4], o1a[4];
#pragma unroll
        for (int j = 0; j < 4; ++j) {
            float d0 = e0[j] - z0a[j];
            float d1 = e1[j] - z1a[j];
            o0a[j] = z0a[j] + d0;            // straight-through fwd
            o1a[j] = z1a[j] + d1;
            s_sq = fmaf(d0, d0, s_sq);
            s_sq = fmaf(d1, d1, s_sq);
            s_d += d0 + d1;
        }
        *(float4*)(oa + hw) = (float4){o0a[0], o0a[1], o0a[2], o0a[3]};
        *(float4*)(ob + hw) = (float4){o1a[0], o1a[1], o1a[2], o1a[3]};
    }
#pragma unroll
    for (int off = 32; off > 0; off >>= 1) {
        s_sq += __shfl_down(s_sq, off, 64);
        s_d  += __shfl_down(s_d,  off, 64);
    }
    if (L == 0) {
        atomicAdd(&lsum[0], s_sq);
        atomicAdd(&lsum[1], s_d);
    }
    __syncthreads();
    if (tid == 0) {
        atomicAdd(&acc_loss[0], lsum[0]);
        atomicAdd(&acc_loss[1], lsum[1]);
    }
}

// --- kernel 4: finalize scalar loss ---
__global__ void loss_kernel(const float* __restrict__ acc_loss,
                            float* __restrict__ out_loss) {
    out_loss[0] = acc_loss[0] * NTOT_INV + BETA * (acc_loss[1] * NTOT_INV);
}

extern "C" void kernel_launch(void* const* d_in, const int* in_sizes, int n_in,
                              void* d_out, int out_size, void* d_ws, size_t ws_size,
                              hipStream_t stream) {
    const float* z   = (const float*)d_in[0];   // [64,256,32,32]
    const float* emb = (const float*)d_in[1];   // [1024,256]
    float* out = (float*)d_out;                 // [16777216 z_q] + [1 loss]
    float* ws  = (float*)d_ws;
    float* acc  = ws;                               // 2 floats
    float* esq1 = ws + 64;                          // 1024 floats
    short* ebf2 = (short*)(ws + 64 + 1024);         // 512 KB (tiled codebook)
    unsigned short* inds = (unsigned short*)(ebf2 + (size_t)K * C);  // 128 KB

    prep_kernel<<<dim3(K / 4), 256, 0, stream>>>(emb, ebf2, esq1, acc);
    vq_dist<<<dim3(1024), 256, 0, stream>>>(z, ebf2, esq1, inds);
    vq_out<<<dim3(2048), 256, 0, stream>>>(z, emb, inds, out, acc);
    loss_kernel<<<1, 1, 0, stream>>>(acc, out + (size_t)B * C * HW);
}

// Round 6
// 191.883 us; speedup vs baseline: 1.4994x; 1.4994x over previous
//
#include <hip/hip_runtime.h>
#include <hip/hip_bf16.h>
#include <float.h>

// Problem constants
constexpr int B  = 64;
constexpr int C  = 256;
constexpr int HW = 1024;   // 32*32
constexpr int K  = 1024;
constexpr float BETA = 0.25f;
constexpr float NTOT_INV = 1.0f / 16777216.0f;  // 1 / (64*256*32*32)

typedef __attribute__((ext_vector_type(8))) short bf16x8;
typedef __attribute__((ext_vector_type(4))) float floatx4;

union U16 { uint4 u; bf16x8 b; };

__device__ inline unsigned short f2bf(float x) {
    unsigned u = __float_as_uint(x);
    return (unsigned short)((u + 0x7FFFu + ((u >> 16) & 1u)) >> 16);  // RNE
}

// --- kernel 1: emb fp32 -> bf16 TILED [ks][code][32ch] + esq1 + esum ---
// esq1[k] = 1 + ||e_k||^2 (fp32); esum[k] = sum_c e_k[c] (for commitment loss).
// grid 256 x 256 threads. Also zeroes loss accumulators.
__global__ __launch_bounds__(256) void prep_kernel(const float* __restrict__ emb,
                                                   short* __restrict__ ebf2,
                                                   float* __restrict__ esq1,
                                                   float* __restrict__ esum,
                                                   float* __restrict__ acc_loss) {
    if (blockIdx.x == 0 && threadIdx.x < 2) acc_loss[threadIdx.x] = 0.0f;
    const int wid  = threadIdx.x >> 6;
    const int lane = threadIdx.x & 63;
    const int k    = blockIdx.x * 4 + wid;
    const float4 v = *(const float4*)(emb + (size_t)k * C + lane * 4);
    ushort4 pk = { f2bf(v.x), f2bf(v.y), f2bf(v.z), f2bf(v.w) };
    *(ushort4*)&ebf2[((size_t)(lane >> 3) * K + k) * 32 + (lane & 7) * 4] = pk;
    float s  = v.x * v.x + v.y * v.y + v.z * v.z + v.w * v.w;
    float s2 = v.x + v.y + v.z + v.w;
#pragma unroll
    for (int off = 32; off > 0; off >>= 1) {
        s  += __shfl_down(s,  off, 64);
        s2 += __shfl_down(s2, off, 64);
    }
    if (lane == 0) { esq1[k] = 1.0f + s; esum[k] = s2; }
}

// --- kernel 2: z NCHW f32 -> zt2 slabs (exact vq_dist LDS layout) + zsq + sum(z).
// zt2 slab per 64-token block TB: [kq=32][tokL=64][8ch] bf16 = 32KB.
// All global reads/writes are 1KB-contiguous wave bursts. zsq computed in fp32
// BEFORE bf16 rounding. grid 256 blocks (b, hw-quarter) x 512 threads.
__global__ __launch_bounds__(512) void zt_kernel(const float* __restrict__ z,
                                                 short* __restrict__ zt2,
                                                 float* __restrict__ zsq,
                                                 float* __restrict__ acc_loss) {
    __shared__ unsigned int U[256 * 33];   // 33 KB (+1 pad col: conflict-free reads)
    __shared__ float zsqP[8][256];         // 8 KB per-wave zsq partials
    __shared__ float zsums[8];
    const int tid = threadIdx.x;           // 0..511
    const int wv  = tid >> 6;              // wave 0..7
    const int L   = tid & 63;
    const int b   = blockIdx.x >> 2;
    const int quarter = blockIdx.x & 3;
    const int hw0 = quarter * 256;
    const float* zb = z + (size_t)b * C * HW;
    const int TB0 = b * 16 + quarter * 4;  // first of 4 token-blocks

    float zq4[4] = {0.f, 0.f, 0.f, 0.f};
    float zs = 0.f;

    for (int ch0 = 0; ch0 < C; ch0 += 64) {
        // stage-in: wave wv reads channels ch0+wv*8 .. +7, each one 1KB burst
        float4 va[8];
#pragma unroll
        for (int i = 0; i < 8; ++i) {
            const int c = ch0 + wv * 8 + i;
            va[i] = *(const float4*)(zb + (size_t)c * HW + hw0 + L * 4);
        }
        // fp32 loss partials (pre-rounding): tokens 4L..4L+3
#pragma unroll
        for (int i = 0; i < 8; ++i) {
            const float* p = (const float*)&va[i];
#pragma unroll
            for (int j = 0; j < 4; ++j) { zq4[j] = fmaf(p[j], p[j], zq4[j]); zs += p[j]; }
        }
#pragma unroll
        for (int i = 0; i < 8; i += 2) {
            const int cu = (wv * 8 + i) >> 1;          // channel-pair column
            const float* p0 = (const float*)&va[i];
            const float* p1 = (const float*)&va[i + 1];
#pragma unroll
            for (int j = 0; j < 4; ++j) {
                unsigned int u = ((unsigned int)f2bf(p0[j])) |
                                 ((unsigned int)f2bf(p1[j]) << 16);
                U[(L * 4 + j) * 33 + cu] = u;
            }
        }
        __syncthreads();
        // stage-out: slot -> (t4, ksl, q, tokL); consecutive tid -> consecutive
        // 16B granules of one (TB, kq) row => 1KB contiguous per wave.
#pragma unroll
        for (int r = 0; r < 4; ++r) {
            const int slot = r * 512 + tid;
            const int t4   = slot >> 9;
            const int ksl  = (slot >> 8) & 1;
            const int qq   = (slot >> 6) & 3;
            const int tokL = slot & 63;
            const int tokl = t4 * 64 + tokL;
            const int cb   = ksl * 16 + qq * 4;
            uint4 w;
            w.x = U[tokl * 33 + cb + 0];
            w.y = U[tokl * 33 + cb + 1];
            w.z = U[tokl * 33 + cb + 2];
            w.w = U[tokl * 33 + cb + 3];
            const int kq = ((ch0 >> 5) + ksl) * 4 + qq;
            *(uint4*)&zt2[(size_t)(TB0 + t4) * 16384 + kq * 512 + tokL * 8] = w;
        }
        __syncthreads();
    }

    // zsq: combine the 8 waves' channel-partials per token
#pragma unroll
    for (int j = 0; j < 4; ++j) zsqP[wv][L * 4 + j] = zq4[j];
#pragma unroll
    for (int off = 32; off > 0; off >>= 1) zs += __shfl_down(zs, off, 64);
    if (L == 0) zsums[wv] = zs;
    __syncthreads();
    if (tid < 256) {
        float s = 0.f;
#pragma unroll
        for (int w = 0; w < 8; ++w) s += zsqP[w][tid];
        zsq[(size_t)b * HW + hw0 + tid] = s;
    }
    if (tid == 0) {
        float t = 0.f;
#pragma unroll
        for (int w = 0; w < 8; ++w) t += zsums[w];
        atomicAdd(&acc_loss[1], -t);   // s_d = sum(esum[km]) - sum(z)
    }
}

// --- kernel 3: distances + argmin + loss terms. 4 waves/block, 64 tokens,
// wave w handles codes [w*256, +256). Phase 1 is a pure coalesced 32KB
// slab->LDS copy (zt2 is pre-transposed). (256,2): ~190-reg body, NO spill
// (any tighter cap spills: R1/R5 regressions). grid 1024 x 256.
__global__ __launch_bounds__(256, 2) void vq_dist(const short* __restrict__ zt2,
                                                  const short* __restrict__ ebf2,
                                                  const float* __restrict__ esq1,
                                                  const float* __restrict__ esum,
                                                  const float* __restrict__ zsq,
                                                  unsigned short* __restrict__ inds,
                                                  float* __restrict__ acc_loss) {
    __shared__ short Zs[32 * 512];          // 32 KB, layout [kq][tokL][8ch]
    __shared__ unsigned int warr[4 * 64];

    const int tid = threadIdx.x;
    const int wid = tid >> 6;
    const int L   = tid & 63;
    const int q   = L >> 4;
    const int l15 = L & 15;
    const int TB  = blockIdx.x;
    const int tok0 = TB * 64;

    // ---- phase 1: coalesced slab copy (8 x uint4 per thread) ----
    const short* src = zt2 + (size_t)TB * 16384;
#pragma unroll
    for (int i = 0; i < 8; ++i) {
        const int g = i * 256 + tid;
        *(uint4*)&Zs[g * 8] = *(const uint4*)&src[g * 8];
    }
    __syncthreads();

    // ---- phase 2: K loop (identical to proven R3 inner loop) ----
    unsigned int best[4] = {0xFFFFFFFFu, 0xFFFFFFFFu, 0xFFFFFFFFu, 0xFFFFFFFFu};

    for (int kk = 0; kk < 4; ++kk) {
        const int k0 = wid * 256 + kk * 64;
        floatx4 acc[4][4];
#pragma unroll
        for (int m = 0; m < 4; ++m)
#pragma unroll
            for (int t = 0; t < 4; ++t) acc[m][t] = (floatx4){0.f, 0.f, 0.f, 0.f};

#pragma unroll
        for (int ks = 0; ks < 8; ++ks) {
            U16 a[4];
#pragma unroll
            for (int m = 0; m < 4; ++m)
                a[m].u = *(const uint4*)(ebf2 + ((size_t)ks * K + (k0 + m * 16 + l15)) * 32 + q * 8);
            bf16x8 zf[4];
#pragma unroll
            for (int t = 0; t < 4; ++t)
                zf[t] = *(const bf16x8*)&Zs[(ks * 4 + q) * 512 + (t * 16 + l15) * 8];
#pragma unroll
            for (int m = 0; m < 4; ++m)
#pragma unroll
                for (int t = 0; t < 4; ++t)
                    acc[m][t] = __builtin_amdgcn_mfma_f32_16x16x32_bf16(a[m].b, zf[t], acc[m][t], 0, 0, 0);
        }

        // d = 1 + ||e||^2 - 2 z.e  (positive => bit-monotone); low 10 bits = code
#pragma unroll
        for (int m = 0; m < 4; ++m) {
            const float4 eq = *(const float4*)&esq1[k0 + m * 16 + q * 4];
            const float eqa[4] = {eq.x, eq.y, eq.z, eq.w};
#pragma unroll
            for (int r = 0; r < 4; ++r) {
                const unsigned int code = (unsigned int)(k0 + m * 16 + q * 4 + r);
#pragma unroll
                for (int t = 0; t < 4; ++t) {
                    float d = fmaf(-2.0f, acc[m][t][r], eqa[r]);
                    unsigned int u = (__float_as_uint(d) & 0xFFFFFC00u) | code;
                    best[t] = best[t] < u ? best[t] : u;
                }
            }
        }
    }

    // ---- phase 3: argmin reduce; epilogue computes loss terms from d_min ----
#pragma unroll
    for (int t = 0; t < 4; ++t) {
        unsigned int o = (unsigned int)__shfl_xor((int)best[t], 16, 64);
        best[t] = best[t] < o ? best[t] : o;
        o = (unsigned int)__shfl_xor((int)best[t], 32, 64);
        best[t] = best[t] < o ? best[t] : o;
    }
    warr[wid * 64 + L] = (q == 0) ? best[0] : (q == 1) ? best[1] : (q == 2) ? best[2] : best[3];
    __syncthreads();

    if (tid < 64) {
        unsigned int u0 = warr[tid];
        unsigned int u1 = warr[64 + tid];
        unsigned int u2 = warr[128 + tid];
        unsigned int u3 = warr[192 + tid];
        u0 = u0 < u1 ? u0 : u1;
        u2 = u2 < u3 ? u2 : u3;
        u0 = u0 < u2 ? u0 : u2;
        const int km = (int)(u0 & 1023u);
        inds[tok0 + tid] = (unsigned short)km;
        // ||e_km - z||^2 = (d_min - 1) + ||z||^2   (zsq is fp32, pre-rounding)
        const float d = __uint_as_float(u0 & 0xFFFFFC00u);
        float ssq = d - 1.0f + zsq[tok0 + tid];
        float sd  = esum[km];
#pragma unroll
        for (int off = 32; off > 0; off >>= 1) {
            ssq += __shfl_down(ssq, off, 64);
            sd  += __shfl_down(sd,  off, 64);
        }
        if (tid == 0) {
            atomicAdd(&acc_loss[0], ssq);
            atomicAdd(&acc_loss[1], sd);
        }
    }
}

// --- kernel 4: pure gather-write: out[b][c][hw] = emb[km(b,hw)][c].
// (straight-through forward == z_q exactly; no z traffic, no loss here).
// grid 2048 (b x ch-octet) x 256 threads; out writes are 1KB wave bursts;
// gathers are 2 x float4 per km from the L2-resident 1MB codebook.
__global__ __launch_bounds__(256) void vq_write(const float* __restrict__ emb,
                                                const unsigned short* __restrict__ inds,
                                                float* __restrict__ out) {
    const int tid = threadIdx.x;
    const int wv  = tid >> 6;
    const int L   = tid & 63;
    const int b   = blockIdx.x >> 5;
    const int c0  = (blockIdx.x & 31) * 8;
    const int hw  = wv * 256 + L * 4;

    ushort4 kmv = *(const ushort4*)(inds + b * HW + hw);
    const unsigned short kma[4] = {kmv.x, kmv.y, kmv.z, kmv.w};
    float4 elo[4], ehi[4];
#pragma unroll
    for (int j = 0; j < 4; ++j) {
        const float* er = emb + (size_t)kma[j] * C + c0;
        elo[j] = *(const float4*)er;
        ehi[j] = *(const float4*)(er + 4);
    }
    float* ob = out + ((size_t)b * C + c0) * HW + hw;
#pragma unroll
    for (int cc = 0; cc < 4; ++cc) {
        float4 v = { ((const float*)&elo[0])[cc], ((const float*)&elo[1])[cc],
                     ((const float*)&elo[2])[cc], ((const float*)&elo[3])[cc] };
        *(float4*)(ob + (size_t)cc * HW) = v;
    }
#pragma unroll
    for (int cc = 0; cc < 4; ++cc) {
        float4 v = { ((const float*)&ehi[0])[cc], ((const float*)&ehi[1])[cc],
                     ((const float*)&ehi[2])[cc], ((const float*)&ehi[3])[cc] };
        *(float4*)(ob + (size_t)(4 + cc) * HW) = v;
    }
}

// --- kernel 5: finalize scalar loss ---
__global__ void loss_kernel(const float* __restrict__ acc_loss,
                            float* __restrict__ out_loss) {
    out_loss[0] = acc_loss[0] * NTOT_INV + BETA * (acc_loss[1] * NTOT_INV);
}

extern "C" void kernel_launch(void* const* d_in, const int* in_sizes, int n_in,
                              void* d_out, int out_size, void* d_ws, size_t ws_size,
                              hipStream_t stream) {
    const float* z   = (const float*)d_in[0];   // [64,256,32,32]
    const float* emb = (const float*)d_in[1];   // [1024,256]
    float* out = (float*)d_out;                 // [16777216 z_q] + [1 loss]
    float* ws  = (float*)d_ws;
    float* acc  = ws;                               // 2 floats
    float* esq1 = ws + 64;                          // 1024 floats
    float* esum = ws + 64 + 1024;                   // 1024 floats
    short* ebf2 = (short*)(ws + 64 + 2048);         // 512 KB (tiled codebook)
    unsigned short* inds = (unsigned short*)(ebf2 + (size_t)K * C);  // 128 KB
    // Scratch in the out buffer (consumed by vq_dist before vq_write overwrites):
    short* zt2 = (short*)out;                       // 33.5 MB (slab-layout z)
    float* zsq = out + (size_t)12 * 1024 * 1024;    // 256 KB at 48MB offset

    prep_kernel<<<dim3(K / 4), 256, 0, stream>>>(emb, ebf2, esq1, esum, acc);
    zt_kernel<<<dim3(256), 512, 0, stream>>>(z, zt2, zsq, acc);
    vq_dist<<<dim3(1024), 256, 0, stream>>>(zt2, ebf2, esq1, esum, zsq, inds, acc);
    vq_write<<<dim3(2048), 256, 0, stream>>>(emb, inds, out);
    loss_kernel<<<1, 1, 0, stream>>>(acc, out + (size_t)B * C * HW);
}